// Round 1
// baseline (661.765 us; speedup 1.0000x reference)
//
#include <hip/hip_runtime.h>
#include <stdint.h>

#define HDIM 4096
#define WDIM 4096
#define HWN (HDIM*WDIM)
#define NBIN 512

// ---------------- init: zero binstats, init minmax ----------------
__global__ void init_kernel(float* __restrict__ binstats, int* __restrict__ minmax) {
    int t = threadIdx.x;
    for (int i = t; i < 5 * NBIN; i += 256) binstats[i] = 0.f;
    if (t < 3) { minmax[t] = 0x7F800000; minmax[3 + t] = 0; }  // +inf bits / 0 (all vals >= 0)
}

// ---------------- pass A: per-channel min/max of raw image ----------------
__global__ void __launch_bounds__(256) minmax_kernel(const float* __restrict__ img,
                                                     int* __restrict__ minmax) {
    const int c = blockIdx.y;
    const float4* p = (const float4*)(img + (size_t)c * HWN);
    const int n4 = HWN / 4;
    float mn = 1e30f, mx = -1e30f;
    for (int i = blockIdx.x * 256 + threadIdx.x; i < n4; i += 256 * gridDim.x) {
        float4 v = p[i];
        mn = fminf(mn, fminf(fminf(v.x, v.y), fminf(v.z, v.w)));
        mx = fmaxf(mx, fmaxf(fmaxf(v.x, v.y), fmaxf(v.z, v.w)));
    }
#pragma unroll
    for (int off = 32; off > 0; off >>= 1) {
        mn = fminf(mn, __shfl_down(mn, off));
        mx = fmaxf(mx, __shfl_down(mx, off));
    }
    __shared__ float smn[4], smx[4];
    int lane = threadIdx.x & 63, wid = threadIdx.x >> 6;
    if (lane == 0) { smn[wid] = mn; smx[wid] = mx; }
    __syncthreads();
    if (threadIdx.x == 0) {
        for (int w = 1; w < 4; w++) { mn = fminf(mn, smn[w]); mx = fmaxf(mx, smx[w]); }
        // values are non-negative floats -> int-pattern compare == float compare
        atomicMin(&minmax[c], __float_as_int(mn));
        atomicMax(&minmax[3 + c], __float_as_int(mx));
    }
}

// ---------------- pass B: quantize, write bin map, scatter-sum stats ----------------
__global__ void __launch_bounds__(256) quant_kernel(const float* __restrict__ img,
                                                    const int* __restrict__ minmax,
                                                    uint16_t* __restrict__ linmap,
                                                    float* __restrict__ binstats) {
    __shared__ int qlut[3 * 256];
    __shared__ float s_cnt[NBIN], s_x[NBIN], s_y[NBIN], s_x2[NBIN], s_y2[NBIN];
    for (int i = threadIdx.x; i < NBIN; i += 256) {
        s_cnt[i] = 0.f; s_x[i] = 0.f; s_y[i] = 0.f; s_x2[i] = 0.f; s_y2[i] = 0.f;
    }
    // exact per-integer-lab-value binning LUT: same IEEE f32 division as reference
    for (int i = threadIdx.x; i < 3 * 256; i += 256) {
        int c = i >> 8, t = i & 255;
        float cmn = floorf(__int_as_float(minmax[c]) * 255.f);
        float cmx = floorf(__int_as_float(minmax[3 + c]) * 255.f);
        float step = fmaxf((cmx - cmn) / 8.f, 1e-12f);
        float q = floorf(((float)t - cmn) / step);
        int qi = (int)q;
        qi = qi < 0 ? 0 : (qi > 7 ? 7 : qi);
        qlut[i] = qi;
    }
    __syncthreads();
    const float4* i0 = (const float4*)img;
    const float4* i1 = (const float4*)(img + (size_t)HWN);
    const float4* i2 = (const float4*)(img + (size_t)2 * HWN);
    const int n4 = HWN / 4;
    for (int i = blockIdx.x * 256 + threadIdx.x; i < n4; i += 256 * gridDim.x) {
        float4 a = i0[i], b = i1[i], c = i2[i];
        int p = i * 4;
        float yf = (float)(p >> 12);
        int xb = p & (WDIM - 1);
        float va[4] = {a.x, a.y, a.z, a.w};
        float vb[4] = {b.x, b.y, b.z, b.w};
        float vc[4] = {c.x, c.y, c.z, c.w};
        unsigned short ls[4];
#pragma unroll
        for (int j = 0; j < 4; j++) {
            int l0 = (int)floorf(va[j] * 255.f); l0 = l0 < 0 ? 0 : (l0 > 255 ? 255 : l0);
            int l1 = (int)floorf(vb[j] * 255.f); l1 = l1 < 0 ? 0 : (l1 > 255 ? 255 : l1);
            int l2 = (int)floorf(vc[j] * 255.f); l2 = l2 < 0 ? 0 : (l2 > 255 ? 255 : l2);
            int bin = (qlut[l0] << 6) | (qlut[256 + l1] << 3) | qlut[512 + l2];
            ls[j] = (unsigned short)bin;
            float xf = (float)(xb + j);
            atomicAdd(&s_cnt[bin], 1.f);
            atomicAdd(&s_x[bin], xf);
            atomicAdd(&s_y[bin], yf);
            atomicAdd(&s_x2[bin], xf * xf);
            atomicAdd(&s_y2[bin], yf * yf);
        }
        ushort4 lv; lv.x = ls[0]; lv.y = ls[1]; lv.z = ls[2]; lv.w = ls[3];
        ((ushort4*)linmap)[i] = lv;
    }
    __syncthreads();
    for (int i = threadIdx.x; i < NBIN; i += 256) {
        atomicAdd(&binstats[i], s_cnt[i]);
        atomicAdd(&binstats[NBIN + i], s_x[i]);
        atomicAdd(&binstats[2 * NBIN + i], s_y[i]);
        atomicAdd(&binstats[3 * NBIN + i], s_x2[i]);
        atomicAdd(&binstats[4 * NBIN + i], s_y2[i]);
    }
}

// ---------------- pass C: 512-bin color-space math (single block) ----------------
__global__ void __launch_bounds__(512) binproc_kernel(const float* __restrict__ binstats,
                                                      const int* __restrict__ minmax,
                                                      float* __restrict__ norm_sal) {
    __shared__ float sh[NBIN], sx[NBIN], sy[NBIN], sx2[NBIN], sy2[NBIN];
    __shared__ float salm[NBIN], maskf[NBIN];
    __shared__ float e0[8], e1[8], e2[8];
    __shared__ float rmn[8], rmx[8];
    const int b = threadIdx.x;
    sh[b]  = binstats[b];
    sx[b]  = binstats[NBIN + b];
    sy[b]  = binstats[2 * NBIN + b];
    sx2[b] = binstats[3 * NBIN + b];
    sy2[b] = binstats[4 * NBIN + b];
    if (b < 24) {
        int c = b >> 3, k = b & 7;
        float cmn = floorf(__int_as_float(minmax[c]) * 255.f);
        float cmx = floorf(__int_as_float(minmax[3 + c]) * 255.f);
        float step = fmaxf((cmx - cmn) / 8.f, 1e-12f);
        float e = cmn + (float)k * step;
        if (c == 0) e0[k] = e; else if (c == 1) e1[k] = e; else e2[k] = e;
    }
    __syncthreads();
    const float c0 = e0[b >> 6], c1 = e1[(b >> 3) & 7], c2 = e2[b & 7];
    float contrast = 0.f, en = 0.f, ex = 0.f, ey = 0.f, ex2 = 0.f, ey2 = 0.f;
    for (int j = 0; j < NBIN; j++) {
        float d0 = c0 - e0[j >> 6], d1 = c1 - e1[(j >> 3) & 7], d2c = c2 - e2[j & 7];
        float d2 = d0 * d0 + d1 * d1 + d2c * d2c;
        float D = sqrtf(d2);
        float E = __expf(-d2 * (1.f / 512.f));
        float h = sh[j];
        contrast += D * h; en += E * h;
        ex += E * sx[j]; ey += E * sy[j]; ex2 += E * sx2[j]; ey2 += E * sy2[j];
    }
    float norm = fmaxf(en, 1e-8f);
    float mx = ex / norm, my = ey / norm, mx2 = ex2 / norm, my2 = ey2 / norm;
    float vx = fmaxf(mx2 - mx * mx, 0.f), vy = fmaxf(my2 - my * my, 0.f);
    float g0 = sqrtf(12.f * vx) / 4096.f;
    float g1 = sqrtf(12.f * vy) / 4096.f;
    float g2 = (mx - 2048.f) / 4096.f;
    float g3 = (my - 2048.f) / 4096.f;
    const float CI[4][4] = {{43.3777f, 1.7633f, -0.4059f, 1.0997f},
                            {1.7633f, 40.7221f, -0.0165f, 0.0447f},
                            {-0.4059f, -0.0165f, 87.0455f, -3.2744f},
                            {1.0997f, 0.0447f, -3.2744f, 125.1503f}};
    float xc[4] = {g0 - 0.5555f, g1 - 0.6449f, g2 - 0.0002f, g3 - 0.0063f};
    float maha = 0.f;
#pragma unroll
    for (int ii = 0; ii < 4; ii++)
#pragma unroll
        for (int jj = 0; jj < 4; jj++) maha += xc[ii] * CI[ii][jj] * xc[jj];
    float sp = __expf(-0.5f * maha);
    float sal = contrast * sp;
    float mf = sh[b] > 0.f ? 1.f : 0.f;
    salm[b] = sal * mf;
    maskf[b] = mf;
    __syncthreads();
    float num = 0.f, den = 0.f;
    for (int j = 0; j < NBIN; j++) {
        float d0 = c0 - e0[j >> 6], d1 = c1 - e1[(j >> 3) & 7], d2c = c2 - e2[j & 7];
        float d2 = d0 * d0 + d1 * d1 + d2c * d2c;
        float E = __expf(-d2 * (1.f / 512.f));
        num += E * salm[j]; den += E * maskf[j];
    }
    float smoothed = num / fmaxf(den, 1e-8f);
    float vmn = mf > 0.f ? smoothed : INFINITY;
    float vmx = mf > 0.f ? smoothed : -INFINITY;
#pragma unroll
    for (int off = 32; off > 0; off >>= 1) {
        vmn = fminf(vmn, __shfl_down(vmn, off));
        vmx = fmaxf(vmx, __shfl_down(vmx, off));
    }
    int lane = b & 63, wid = b >> 6;
    if (lane == 0) { rmn[wid] = vmn; rmx[wid] = vmx; }
    __syncthreads();
    if (b == 0) {
        float a = rmn[0], z = rmx[0];
        for (int w = 1; w < 8; w++) { a = fminf(a, rmn[w]); z = fmaxf(z, rmx[w]); }
        rmn[0] = a; rmx[0] = z;
    }
    __syncthreads();
    float mnv = rmn[0], mxv = rmx[0];
    float ns = (mxv > mnv) ? 255.f * (smoothed - mnv) / fmaxf(mxv - mnv, 1e-30f) : 0.f;
    norm_sal[b] = ns;
}

// ---------------- pass D: gather + horizontal 10-tap sum ----------------
#define RPB 4
__global__ void __launch_bounds__(256) hblur_kernel(const uint16_t* __restrict__ linmap,
                                                    const float* __restrict__ norm_sal,
                                                    float* __restrict__ temp) {
    __shared__ float lut[NBIN];
    __shared__ float sv[256 + 9];
    for (int i = threadIdx.x; i < NBIN; i += 256) lut[i] = norm_sal[i];
    const int x0 = blockIdx.x * 256;
    for (int r = 0; r < RPB; r++) {
        const int y = blockIdx.y * RPB + r;
        __syncthreads();
        for (int t = threadIdx.x; t < 265; t += 256) {
            int v = x0 - 5 + t;
            v = v < 0 ? -v : (v >= WDIM ? 2 * WDIM - 2 - v : v);  // reflect-101
            sv[t] = lut[linmap[(size_t)y * WDIM + v]];
        }
        __syncthreads();
        float s = 0.f;
#pragma unroll
        for (int k = 0; k < 10; k++) s += sv[threadIdx.x + k];
        temp[(size_t)y * WDIM + x0 + threadIdx.x] = s;
    }
}

// ---------------- pass E: vertical 10-tap sliding sum + scale ----------------
#define YB 64
__global__ void __launch_bounds__(256) vblur_kernel(const float* __restrict__ temp,
                                                    float* __restrict__ out) {
    const int x = blockIdx.x * 256 + threadIdx.x;
    const int y0 = blockIdx.y * YB;
    float s = 0.f;
#pragma unroll
    for (int u = y0 - 5; u < y0 + 5; u++) {
        int ur = u < 0 ? -u : (u >= HDIM ? 2 * HDIM - 2 - u : u);
        s += temp[(size_t)ur * WDIM + x];
    }
    for (int yy = y0; yy < y0 + YB; yy++) {
        out[(size_t)yy * WDIM + x] = s * (1.f / 100.f) * (1.f / 255.f);
        int ua = yy + 5, ub = yy - 5;
        int ura = ua >= HDIM ? 2 * HDIM - 2 - ua : ua;
        int urb = ub < 0 ? -ub : ub;
        s += temp[(size_t)ura * WDIM + x] - temp[(size_t)urb * WDIM + x];
    }
}

extern "C" void kernel_launch(void* const* d_in, const int* in_sizes, int n_in,
                              void* d_out, int out_size, void* d_ws, size_t ws_size,
                              hipStream_t stream) {
    const float* img = (const float*)d_in[0];
    float* out = (float*)d_out;
    char* ws = (char*)d_ws;
    // ws layout: linmap (2*HWN) | temp (4*HWN) | binstats (5*512*4) | minmax (24) | norm_sal (2048)
    uint16_t* linmap = (uint16_t*)ws;
    float* temp = (float*)(ws + (size_t)2 * HWN);
    float* binstats = (float*)(ws + (size_t)6 * HWN);
    int* minmax = (int*)(ws + (size_t)6 * HWN + 10240);
    float* norm_sal = (float*)(ws + (size_t)6 * HWN + 10240 + 256);

    init_kernel<<<1, 256, 0, stream>>>(binstats, minmax);
    minmax_kernel<<<dim3(256, 3), 256, 0, stream>>>(img, minmax);
    quant_kernel<<<512, 256, 0, stream>>>(img, minmax, linmap, binstats);
    binproc_kernel<<<1, 512, 0, stream>>>(binstats, minmax, norm_sal);
    hblur_kernel<<<dim3(WDIM / 256, HDIM / RPB), 256, 0, stream>>>(linmap, norm_sal, temp);
    vblur_kernel<<<dim3(WDIM / 256, HDIM / YB), 256, 0, stream>>>(temp, out);
}